// Round 12
// baseline (172.314 us; speedup 1.0000x reference)
//
#include <hip/hip_runtime.h>
#include <hip/hip_bf16.h>

// Sobel edge detection, promote: x[32,3,512,512] f32 -> edge[32,1,512,512] f32 (0/1)
// edge = OR_c ( sqrt(gx^2+gy^2) > 0.2 ) = ( sqrtf( max_c(gx^2+gy^2) ) > 0.2 )
//
// MEASURED LADDER:
//  R3:  4x8 tile, 160 VGPR -> 3 waves/SIMD, Occ 9.8%, 17% HBM, kernel 64 us
//  R6:  2x4 tile, bounds(256,6) -> VGPR 40, SPILLS (WRITE 240MB), 132 us
//  R11: 2x4 tile, bounds(256,4) -> kernel ~47 us (bench 153.7 - ~107 overhead;
//       kernel now faster than the 58us poison-fills, so hidden from top-5).
//       Fills calibrate achievable BW: 6.9 TB/s. Floor ~20 us for 134 MB.
//  R12 (this): halo values via wave shuffles instead of scalar gather loads.
//       Within a wave, wq is consecutive and h0 uniform -> left halo =
//       __shfl_up(m.w,1), right halo = __shfl_down(m.x,1); only lanes 0/63
//       need a fixup load. Memory instrs/thread: 36 -> 12 (+2 stores).

#define H 512
#define W 512
#define C 3
#define B 32

__global__ __launch_bounds__(256, 4) void sobel_edge_kernel(
    const float* __restrict__ x, float* __restrict__ out) {
    // tid -> (b, hq, wq): wq in [0,128) (4-col groups), hq in [0,256) (2-row groups)
    const int tid = blockIdx.x * blockDim.x + threadIdx.x;
    const int wq = tid & 127;
    const int hq = (tid >> 7) & 255;
    const int b  = tid >> 15;          // 128*256 = 2^15 threads per image

    const int w0 = wq << 2;
    const int h0 = hq << 1;
    const int lane = threadIdx.x & 63;
    const bool has_left  = (w0 > 0);
    const bool has_right = (w0 + 4 < W);
    const float* xb = x + (size_t)b * C * H * W;

    // running max over channels of gx^2+gy^2, per output pixel
    float smax[2][4];
#pragma unroll
    for (int i = 0; i < 2; ++i)
#pragma unroll
        for (int j = 0; j < 4; ++j) smax[i][j] = 0.0f;

#pragma unroll
    for (int c = 0; c < C; ++c) {
        const float* xc = xb + (size_t)c * H * W;

        float dxb[3][4], sxb[3][4];   // rolling 3-row buffers (static idx only)

#pragma unroll
        for (int r = 0; r < 4; ++r) {
            // ---- load input row h0-1+r, cols w0-1 .. w0+4 ----
            // One coalesced float4; halos from neighbor lanes via shuffle
            // (wq consecutive, h0 uniform within a wave). Lanes 0/63 fix up.
            float p[6];
            const int hh = h0 + r - 1;
            if (hh >= 0 && hh < H) {     // wave-uniform branch
                const float* rp = xc + (size_t)hh * W;
                const float4 m = *reinterpret_cast<const float4*>(rp + w0);
                float left  = __shfl_up(m.w, 1);    // lane l-1's w0+3 = our w0-1
                float right = __shfl_down(m.x, 1);  // lane l+1's w0   = our w0+4
                if (lane == 0)  left  = has_left  ? rp[w0 - 1] : 0.0f;
                if (lane == 63) right = has_right ? rp[w0 + 4] : 0.0f;
                p[0] = left;
                p[1] = m.x; p[2] = m.y; p[3] = m.z; p[4] = m.w;
                p[5] = right;
            } else {
#pragma unroll
                for (int k = 0; k < 6; ++k) p[k] = 0.0f;
            }

            // ---- row-wise separable intermediates into rolling slot ----
            const int rr = r % 3;      // compile-time (fully unrolled)
#pragma unroll
            for (int j = 0; j < 4; ++j) {
                dxb[rr][j] = p[j + 2] - p[j];
                sxb[rr][j] = p[j] + 2.0f * p[j + 1] + p[j + 2];
            }

            // ---- once 3 rows live, emit output row i = r-2 ----
            if (r >= 2) {
                const int i  = r - 2;
                const int r0 = (r - 2) % 3;
                const int r1 = (r - 1) % 3;
                const int r2 = rr;
#pragma unroll
                for (int j = 0; j < 4; ++j) {
                    const float gx = dxb[r0][j] + 2.0f * dxb[r1][j] + dxb[r2][j];
                    const float gy = sxb[r2][j] - sxb[r0][j];
                    const float s  = gx * gx + gy * gy;
                    smax[i][j] = fmaxf(smax[i][j], s);
                }
            }
        }
    }

    // ---- threshold + store (1 float4 per output row) ----
    float* ob = out + ((size_t)b * H + h0) * W + w0;
#pragma unroll
    for (int i = 0; i < 2; ++i) {
        float4 o;
        o.x = (sqrtf(smax[i][0]) > 0.2f) ? 1.0f : 0.0f;
        o.y = (sqrtf(smax[i][1]) > 0.2f) ? 1.0f : 0.0f;
        o.z = (sqrtf(smax[i][2]) > 0.2f) ? 1.0f : 0.0f;
        o.w = (sqrtf(smax[i][3]) > 0.2f) ? 1.0f : 0.0f;
        *reinterpret_cast<float4*>(ob + (size_t)i * W) = o;
    }
}

extern "C" void kernel_launch(void* const* d_in, const int* in_sizes, int n_in,
                              void* d_out, int out_size, void* d_ws, size_t ws_size,
                              hipStream_t stream) {
    const float* x = (const float*)d_in[0];
    float* out = (float*)d_out;
    // total threads = 32 * 256 * 128 = 1,048,576 -> 4096 blocks of 256
    const int total = B * (H / 2) * (W / 4);
    const int block = 256;
    const int grid = total / block;  // exact
    sobel_edge_kernel<<<grid, block, 0, stream>>>(x, out);
}

// Round 13
// 158.423 us; speedup vs baseline: 1.0877x; 1.0877x over previous
//
#include <hip/hip_runtime.h>
#include <hip/hip_bf16.h>

// Sobel edge detection, promote: x[32,3,512,512] f32 -> edge[32,1,512,512] f32 (0/1)
// edge = OR_c ( sqrt(gx^2+gy^2) > 0.2 ) = ( sqrtf( max_c(gx^2+gy^2) ) > 0.2 )
//
// MEASURED LADDER:
//  R3:  4x8 tile, 160 VGPR -> 3 waves/SIMD, Occ 9.8%, 17% HBM, 64 us
//  R6:  2x4 tile, bounds(256,6) -> VGPR 40, SPILLS (WRITE 240MB), 132 us
//  R11: 2x4 tile, bounds(256,4), rolling buffer -> ~47 us (hidden under 58us
//       poison-fills; fills calibrate write BW at 6.9 TB/s)
//  R12: + __shfl halos -> 63.3 us REGRESSION. __shfl = ds_bpermute = LDS-pipe
//       op with lgkmcnt latency; 24/thread in the dependency chain. VGPR 60,
//       WRITE clean 32.8MB, Occ 39%, VALU 29%, HBM 21% => latency-bound.
//  R13 (this): revert shuffles; restructure for MLP. Per channel, issue all
//       12 loads (4 rows x {dwordx4 + 2 halo scalars}) as one unconditional
//       branch-free batch (clamped rows, uniform zero-mask on dx/sx), then
//       compute from flat 4-row patch. 12 loads in flight per wave.

#define H 512
#define W 512
#define C 3
#define B 32

__global__ __launch_bounds__(256, 4) void sobel_edge_kernel(
    const float* __restrict__ x, float* __restrict__ out) {
    // tid -> (b, hq, wq): wq in [0,128) (4-col groups), hq in [0,256) (2-row groups)
    const int tid = blockIdx.x * blockDim.x + threadIdx.x;
    const int wq = tid & 127;
    const int hq = (tid >> 7) & 255;
    const int b  = tid >> 15;          // 128*256 = 2^15 threads per image

    const int w0 = wq << 2;
    const int h0 = hq << 1;
    const bool has_left  = (w0 > 0);
    const bool has_right = (w0 + 4 < W);
    const int wl = has_left  ? w0 - 1 : 0;       // clamped halo col (in-bounds)
    const int wr = has_right ? w0 + 4 : W - 1;
    const float* xb = x + (size_t)b * C * H * W;

    // row 0 is h0-1 (may be -1 -> clamped+zeroed); row 3 is h0+2 (may be 512)
    const bool row0_ok = (h0 > 0);
    const bool row3_ok = (h0 + 2 < H);

    float smax[2][4];
#pragma unroll
    for (int i = 0; i < 2; ++i)
#pragma unroll
        for (int j = 0; j < 4; ++j) smax[i][j] = 0.0f;

#pragma unroll
    for (int c = 0; c < C; ++c) {
        const float* xc = xb + (size_t)c * H * W;

        // ---- batch-issue all 12 loads (unconditional, clamped addresses) ----
        float4 m[4];
        float lft[4], rgt[4];
#pragma unroll
        for (int r = 0; r < 4; ++r) {
            const int hh = h0 + r - 1;
            const int hc = (hh < 0) ? 0 : ((hh >= H) ? (H - 1) : hh);  // uniform
            const float* rp = xc + (size_t)hc * W;
            m[r]   = *reinterpret_cast<const float4*>(rp + w0);
            lft[r] = rp[wl];
            rgt[r] = rp[wr];
        }

        // ---- per-row separable intermediates from flat patch ----
        float dx[4][4], sx[4][4];
#pragma unroll
        for (int r = 0; r < 4; ++r) {
            float p[6];
            p[0] = has_left  ? lft[r] : 0.0f;   // cndmask, no branch
            p[1] = m[r].x; p[2] = m[r].y; p[3] = m[r].z; p[4] = m[r].w;
            p[5] = has_right ? rgt[r] : 0.0f;
#pragma unroll
            for (int j = 0; j < 4; ++j) {
                dx[r][j] = p[j + 2] - p[j];
                sx[r][j] = p[j] + 2.0f * p[j + 1] + p[j + 2];
            }
            if (r == 0 && !row0_ok) {           // uniform-per-thread, rare
#pragma unroll
                for (int j = 0; j < 4; ++j) { dx[0][j] = 0.0f; sx[0][j] = 0.0f; }
            }
            if (r == 3 && !row3_ok) {
#pragma unroll
                for (int j = 0; j < 4; ++j) { dx[3][j] = 0.0f; sx[3][j] = 0.0f; }
            }
        }

        // ---- two output rows ----
#pragma unroll
        for (int j = 0; j < 4; ++j) {
            const float gx0 = dx[0][j] + 2.0f * dx[1][j] + dx[2][j];
            const float gy0 = sx[2][j] - sx[0][j];
            smax[0][j] = fmaxf(smax[0][j], gx0 * gx0 + gy0 * gy0);
            const float gx1 = dx[1][j] + 2.0f * dx[2][j] + dx[3][j];
            const float gy1 = sx[3][j] - sx[1][j];
            smax[1][j] = fmaxf(smax[1][j], gx1 * gx1 + gy1 * gy1);
        }
    }

    // ---- threshold + store (1 float4 per output row) ----
    float* ob = out + ((size_t)b * H + h0) * W + w0;
#pragma unroll
    for (int i = 0; i < 2; ++i) {
        float4 o;
        o.x = (sqrtf(smax[i][0]) > 0.2f) ? 1.0f : 0.0f;
        o.y = (sqrtf(smax[i][1]) > 0.2f) ? 1.0f : 0.0f;
        o.z = (sqrtf(smax[i][2]) > 0.2f) ? 1.0f : 0.0f;
        o.w = (sqrtf(smax[i][3]) > 0.2f) ? 1.0f : 0.0f;
        *reinterpret_cast<float4*>(ob + (size_t)i * W) = o;
    }
}

extern "C" void kernel_launch(void* const* d_in, const int* in_sizes, int n_in,
                              void* d_out, int out_size, void* d_ws, size_t ws_size,
                              hipStream_t stream) {
    const float* x = (const float*)d_in[0];
    float* out = (float*)d_out;
    // total threads = 32 * 256 * 128 = 1,048,576 -> 4096 blocks of 256
    const int total = B * (H / 2) * (W / 4);
    const int block = 256;
    const int grid = total / block;  // exact
    sobel_edge_kernel<<<grid, block, 0, stream>>>(x, out);
}